// Round 20
// baseline (106.774 us; speedup 1.0000x reference)
//
#include <hip/hip_runtime.h>

#define SS 128
#define S3 (SS*SS*SS)
#define NBATCH 4
#define LEAK 0.01f
#define BNEPS 1e-4f
#define NTILE 16384          // 4 batches * 16^3 tiles of 8^3
#define MAXSLOT 64

// ---------------- workspace layout (bytes) ----------------
constexpr size_t OFF_DENSE    = 0;                                   // f32 [4][128^3] (NOT zeroed; masked on read)
constexpr size_t OFF_MASKBITS = OFF_DENSE + (size_t)NBATCH*S3*4;     // u32 bitgrid 1MB (zeroed by k_init)
constexpr size_t OFF_X1       = OFF_MASKBITS + (size_t)NBATCH*S3/8;  // f32 [4][8][32^3] (written by stage1)
constexpr size_t OFF_MASK32   = OFF_X1 + (size_t)NBATCH*8*32768*4;   // u8 [4][32^3] (written by conv0)
constexpr size_t OFF_MASK8    = OFF_MASK32 + (size_t)NBATCH*32768;   // u8 [4][8^3]  (written by k_stats1m)
constexpr size_t OFF_P1       = OFF_MASK8 + (size_t)NBATCH*512;      // f32 [256][9]
constexpr size_t OFF_P2       = OFF_P1 + 256*9*4;                    // f32 [256][2]
constexpr size_t OFF_P3       = OFF_P2 + 256*2*4;                    // f32 [64][2]
constexpr size_t OFF_PM       = OFF_P3 + 64*2*4;                     // f32 [16] mask-count partials
constexpr size_t OFF_NBLK     = OFF_PM + 16*4;                       // u32 [16384]
constexpr size_t OFF_LIST     = OFF_NBLK + NTILE*4;                  // u32 [16384][64]
constexpr size_t OFF_X0L      = OFF_LIST + (size_t)NTILE*MAXSLOT*4;  // f32x4 [16384][64]
constexpr size_t OFF_X2       = OFF_X0L + (size_t)NTILE*MAXSLOT*16;  // f32 [4][16][8^3]
constexpr size_t OFF_X3       = OFF_X2 + (size_t)NBATCH*16*512*4;    // f32 [4][32][2^3]

__device__ inline float waveSum(float v) {
#pragma unroll
    for (int off = 32; off; off >>= 1) v += __shfl_xor(v, off, 64);
    return v;
}

// -------- init: zero maskbits (blocks 0..255) + zero occupied dense voxels (rest) --------
__global__ void k_init(const float* __restrict__ pc, float* __restrict__ dense,
                       uint4* __restrict__ maskbits4, int n) {
    int blk = blockIdx.x;
    if (blk < 256) {
        maskbits4[blk * 256 + threadIdx.x] = make_uint4(0u, 0u, 0u, 0u);
        return;
    }
    int i = (blk - 256) * 256 + threadIdx.x;
    if (i >= n) return;
    int d = (int)pc[i*5+0], h = (int)pc[i*5+1], w = (int)pc[i*5+2], b = (int)pc[i*5+3];
    dense[(((size_t)b*SS + d)*SS + h)*SS + w] = 0.f;
}

// -------- accumulate features; dedup via bit grid --------
__global__ void k_scatter(const float* __restrict__ pc, float* __restrict__ dense,
                          unsigned* __restrict__ maskbits, int n) {
    int i = blockIdx.x * blockDim.x + threadIdx.x;
    if (i >= n) return;
    float c0 = pc[i*5+0], c1 = pc[i*5+1], c2 = pc[i*5+2], cb = pc[i*5+3], f = pc[i*5+4];
    int d = (int)c0, h = (int)c1, w = (int)c2, b = (int)cb;
    unsigned vox = (((unsigned)b*SS + d)*SS + h)*SS + w;
    atomicAdd(&dense[vox], f);
    atomicOr(&maskbits[vox >> 5], 1u << (vox & 31));
}

// -------- conv0: 8x8x64(+halo) slab per block; float4 staging; sparse queue compute --------
// grid: (16 h-tiles, 16 d-tiles, 4 batches * 2 w-halves), 512 threads
__global__ __launch_bounds__(512) void k_conv0(const float* __restrict__ dense,
                                               const unsigned* __restrict__ maskbits,
                                               const float* __restrict__ w0g,
                                               unsigned* __restrict__ nblk,
                                               unsigned* __restrict__ list,
                                               float4* __restrict__ x0l,
                                               unsigned char* __restrict__ mask32) {
    __shared__ float lds[10*10*68];           // halo slab: col 0 = w0-1, 1..64 = w0.., 65 = w0+64
    __shared__ float ws[108];
    __shared__ unsigned short wtot[8][8];     // per-subtile per-wave occupied counts
    __shared__ unsigned queue[8*MAXSLOT];     // compact work items
    __shared__ unsigned char cellocc[8][8];
    int tid = threadIdx.x;
    int lane = tid & 63, wid = tid >> 6;
    int th = blockIdx.x, td = blockIdx.y;
    int zb = blockIdx.z;                      // b*2 + wh
    int b = zb >> 1, wh = zb & 1;
    int d0 = td*8, h0 = th*8, w0 = wh*64;
    if (tid < 108) ws[tid] = w0g[tid];
    if (tid < 64) cellocc[tid>>3][tid&7] = 0;
    const float* dn = dense + (size_t)b * S3;
    // stage main slab: 100 rows x 16 float4 (mask-gated); thread-linear (row,quad)
    for (int idx = tid; idx < 1600; idx += 512) {
        int r = idx >> 4, q = idx & 15;
        int dz = r / 10, dy = r - dz*10;
        int gz = d0 - 1 + dz, gy = h0 - 1 + dy;
        float4 v = make_float4(0.f, 0.f, 0.f, 0.f);
        if ((unsigned)gz < SS && (unsigned)gy < SS) {
            unsigned row = ((unsigned)b*SS + gz)*SS + gy;
            int gx = w0 + q*4;
            v = *(const float4*)(dn + ((size_t)gz*SS + gy)*SS + gx);
            unsigned mword = maskbits[row*4 + (gx >> 5)];
            int sh = gx & 31;
            if (!((mword >> (sh+0)) & 1u)) v.x = 0.f;
            if (!((mword >> (sh+1)) & 1u)) v.y = 0.f;
            if (!((mword >> (sh+2)) & 1u)) v.z = 0.f;
            if (!((mword >> (sh+3)) & 1u)) v.w = 0.f;
        }
        float* lrow = lds + r*68 + 1 + q*4;
        lrow[0]=v.x; lrow[1]=v.y; lrow[2]=v.z; lrow[3]=v.w;
    }
    // halo columns: 100 rows x 2 sides
    for (int idx = tid; idx < 200; idx += 512) {
        int r = idx >> 1, side = idx & 1;
        int dz = r / 10, dy = r - dz*10;
        int gz = d0 - 1 + dz, gy = h0 - 1 + dy;
        int hgx = side ? (w0 + 64) : (w0 - 1);
        float hv = 0.f;
        if ((unsigned)gz < SS && (unsigned)gy < SS && (unsigned)hgx < SS) {
            unsigned row = ((unsigned)b*SS + gz)*SS + gy;
            float v = dn[((size_t)gz*SS + gy)*SS + hgx];
            unsigned mword = maskbits[row*4 + (hgx >> 5)];
            hv = ((mword >> (hgx & 31)) & 1u) ? v : 0.f;
        }
        lds[r*68 + (side ? 65 : 0)] = hv;
    }
    // occupancy scan: 8 subtile occ bits from this half's two mask words
    int tz = wid, ty = (tid >> 3) & 7, tx = tid & 7;
    int gz = d0 + tz, gy = h0 + ty;
    uint4 rb = ((const uint4*)maskbits)[((unsigned)b*SS + gz)*SS + gy];
    unsigned loW = wh ? rb.z : rb.x;          // words for w0..w0+31 / +32..+63
    unsigned hiW = wh ? rb.w : rb.y;
    unsigned occ8 = 0;
#pragma unroll
    for (int s=0;s<8;++s) {
        unsigned word = (s < 4) ? loW : hiW;
        occ8 |= (((word >> (((s&3)<<3) + tx)) & 1u) << s);
    }
    unsigned long long ballArr[8];
#pragma unroll
    for (int s=0;s<8;++s) {
        ballArr[s] = __ballot((occ8 >> s) & 1u);
        if (lane == 0) wtot[s][wid] = (unsigned short)__popcll(ballArr[s]);
    }
    __syncthreads();   // slab staged; wtot, cellocc-zero visible
    unsigned long long lmask = (1ull << lane) - 1ull;
    int blkbase = ((b*16 + td)*16 + th)*16 + wh*8;
    unsigned qb = 0;   // running queue offset (uniform across block)
#pragma unroll
    for (int s=0;s<8;++s) {
        unsigned base = 0, total = 0;
#pragma unroll
        for (int j=0;j<8;++j) { unsigned t = wtot[s][j]; if (j < wid) base += t; total += t; }
        unsigned tc = total < MAXSLOT ? total : MAXSLOT;
        if ((occ8 >> s) & 1u) {
            unsigned slot = base + (unsigned)__popcll(ballArr[s] & lmask);
            if (slot < MAXSLOT) queue[qb + slot] = (unsigned)tid | (s<<9) | (slot<<13);
            cellocc[s][((tz>>2)<<2) | ((ty>>2)<<1) | (tx>>2)] = 1;
        }
        qb += tc;
    }
    if (tid < 8) {
        unsigned total = 0;
#pragma unroll
        for (int j=0;j<8;++j) total += wtot[tid][j];
        nblk[blkbase + tid] = total < MAXSLOT ? total : MAXSLOT;
    }
    __syncthreads();   // queue + cellocc complete
    if (tid < 64) {
        int s = tid >> 3, c = tid & 7;
        int cz = (c>>2)&1, cy = (c>>1)&1, cx = c&1;
        mask32[b*32768 + ((d0>>2)+cz)*1024 + ((h0>>2)+cy)*32 + wh*16 + s*2+cx] = cellocc[s][c];
    }
    // drain queue: one conv per occupied voxel
    for (unsigned i = tid; i < qb; i += 512) {
        unsigned e = queue[i];
        int et = e & 511, es = (e>>9) & 15, eslot = e >> 13;
        int ez = et >> 6, ey = (et>>3) & 7, ex = et & 7;
        int egx = es*8 + ex;                 // local col within half [0,63]
        float a0=0.f, a1=0.f, a2=0.f, a3=0.f;
#pragma unroll
        for (int kd=0; kd<3; ++kd)
#pragma unroll
            for (int kh=0; kh<3; ++kh)
#pragma unroll
                for (int kw=0; kw<3; ++kw) {
                    float v = lds[((ez+kd)*10 + ey+kh)*68 + egx + kw];
                    int kk = kd*9 + kh*3 + kw;
                    a0 += v*ws[kk]; a1 += v*ws[27+kk]; a2 += v*ws[54+kk]; a3 += v*ws[81+kk];
                }
        int blk = blkbase + es;
        unsigned vox = (((unsigned)b*SS + d0+ez)*SS + h0+ey)*SS + (w0 + egx);
        list[(size_t)blk*MAXSLOT + eslot] = vox;
        x0l[(size_t)blk*MAXSLOT + eslot] = make_float4(a0, a1, a2, a3);
    }
}

// -------- fused: BN1 stats partials (blocks 0..255) + mask8/cnt partials (256..271) --------
__global__ void k_stats1m(const float4* __restrict__ x0l, const unsigned* __restrict__ nblk,
                          const unsigned char* __restrict__ mask32, unsigned char* __restrict__ mask8,
                          float* __restrict__ p1, float* __restrict__ pm) {
    int tid = threadIdx.x;
    int bid = blockIdx.x;
    if (bid < 256) {
        __shared__ float red[4][9];
        int tid0 = bid * 256 + tid;
        float a[9] = {0,0,0,0,0,0,0,0,0};
        for (int s = tid0; s < NTILE*MAXSLOT; s += 65536) {
            int blk = s >> 6, sl = s & 63;
            if (sl < (int)nblk[blk]) {
                float4 v = x0l[s];
                a[0]+=v.x; a[1]+=v.y; a[2]+=v.z; a[3]+=v.w;
                a[4]+=v.x*v.x; a[5]+=v.y*v.y; a[6]+=v.z*v.z; a[7]+=v.w*v.w;
                a[8]+=1.f;
            }
        }
#pragma unroll
        for (int k=0;k<9;++k) a[k] = waveSum(a[k]);
        int wid = tid>>6, lane = tid&63;
        if (lane < 9) red[wid][lane] = a[lane];
        __syncthreads();
        if (tid < 9) p1[bid*9+tid] = red[0][tid]+red[1][tid]+red[2][tid]+red[3][tid];
        return;
    }
    __shared__ float redm[4];
    int blk = bid - 256;
    float c = 0.f;
    if (blk < 8) {          // mask8 + cnt8 partial
        int i = blk*256 + tid;
        int b = i>>9, r = i&511;
        int d8 = r>>6, h8 = (r>>3)&7, w8 = r&7;
        const unsigned char* m = mask32 + b*32768;
        unsigned v = 0;
#pragma unroll
        for (int dz=0;dz<2;++dz)
#pragma unroll
            for (int dy=0;dy<2;++dy)
#pragma unroll
                for (int dx=0;dx<2;++dx)
                    v |= m[(2*d8+dz)*1024 + (2*h8+dy)*32 + (2*w8+dx)];
        mask8[i] = (unsigned char)v;
        c = (float)v;
    } else {                // cnt2 partial: full 128KB of mask32
        const uint4* m4 = (const uint4*)mask32;
        int base = ((blk-8)*256 + tid)*4;
#pragma unroll
        for (int j=0;j<4;++j) {
            uint4 x = m4[base+j];
            c += (float)(__popc(x.x) + __popc(x.y) + __popc(x.z) + __popc(x.w));
        }
    }
    c = waveSum(c);
    if ((tid & 63) == 0) redm[tid>>6] = c;
    __syncthreads();
    if (tid == 0) pm[blk] = redm[0]+redm[1]+redm[2]+redm[3];
}

// -------- stage 1: self-prep BN1 from p1; LDS-accumulated gather -> x1 --------
__global__ void k_stage1(const float4* __restrict__ x0l, const unsigned* __restrict__ list,
                         const unsigned* __restrict__ nblk, const float* __restrict__ wc1,
                         const float* __restrict__ p1, const float* __restrict__ g1,
                         const float* __restrict__ b1, float* __restrict__ x1) {
    __shared__ float acc[256];     // [tile4][o8][cell8]
    __shared__ float wsh[256];
    __shared__ float red[4][9];
    __shared__ float sc[4], sh[4];
    int tid = threadIdx.x;
    int wid = tid>>6, lane = tid&63;
    wsh[tid] = wc1[tid];
    acc[tid] = 0.f;
    float a[9];
#pragma unroll
    for (int k=0;k<9;++k) a[k] = p1[tid*9+k];
#pragma unroll
    for (int k=0;k<9;++k) a[k] = waveSum(a[k]);
    if (lane < 9) red[wid][lane] = a[lane];
    __syncthreads();
    if (tid < 4) {
        float sum = red[0][tid]+red[1][tid]+red[2][tid]+red[3][tid];
        float sq  = red[0][4+tid]+red[1][4+tid]+red[2][4+tid]+red[3][4+tid];
        float cnt = fmaxf(red[0][8]+red[1][8]+red[2][8]+red[3][8], 1.f);
        float mean = sum/cnt, var = sq/cnt - mean*mean;
        float s = g1[tid] * rsqrtf(var + BNEPS);
        sc[tid] = s; sh[tid] = b1[tid] - mean*s;
    }
    __syncthreads();
    int s = blockIdx.x * 256 + tid;
    int blk = s >> 6, sl = s & 63;
    int lt = tid >> 6;
    if (sl < (int)nblk[blk]) {
        unsigned vox = list[s];
        float4 v = x0l[s];
        int w = vox & 127, h = (vox>>7)&127, d = (vox>>14)&127;
        float y[4];
        float t0 = v.x*sc[0]+sh[0]; y[0] = t0 >= 0.f ? t0 : LEAK*t0;
        float t1 = v.y*sc[1]+sh[1]; y[1] = t1 >= 0.f ? t1 : LEAK*t1;
        float t2 = v.z*sc[2]+sh[2]; y[2] = t2 >= 0.f ? t2 : LEAK*t2;
        float t3 = v.w*sc[3]+sh[3]; y[3] = t3 >= 0.f ? t3 : LEAK*t3;
        int widx = (d&1)*4 + (h&1)*2 + (w&1);
        int cell = ((d>>2)&1)*4 + ((h>>2)&1)*2 + ((w>>2)&1);
        float* ap = acc + lt*64 + cell;
#pragma unroll
        for (int o=0;o<8;++o) {
            const float* wp = wsh + o*32 + widx;
            float contrib = y[0]*wp[0] + y[1]*wp[8] + y[2]*wp[16] + y[3]*wp[24];
            atomicAdd(ap + o*8, contrib * 0.125f);
        }
    }
    __syncthreads();
    int rem = tid & 63, o = rem >> 3, cell = rem & 7;
    int blk2 = blockIdx.x*4 + (tid >> 6);
    int ss = blk2 & 15, th = (blk2>>4)&15, td = (blk2>>8)&15, b = blk2>>12;
    int cz = (cell>>2)&1, cy = (cell>>1)&1, cx = cell&1;
    x1[(size_t)b*8*32768 + o*32768 + (td*2+cz)*1024 + (th*2+cy)*32 + ss*2+cx] = acc[tid];
}

// -------- stage-2 stats partials --------
__global__ void k_s2stats(const float4* __restrict__ x1v, float* __restrict__ p2) {
    __shared__ float red[4][2];
    int blk = blockIdx.x;              // 256 = plane(32) x chunk(8)
    int plane = blk >> 3, chunk = blk & 7;
    const float4* p = x1v + (size_t)plane*8192 + chunk*1024;
    float s=0.f, sq=0.f;
    for (int i = threadIdx.x; i < 1024; i += 256) {
        float4 v = p[i];
        s  += v.x+v.y+v.z+v.w;
        sq += v.x*v.x+v.y*v.y+v.z*v.z+v.w*v.w;
    }
    s = waveSum(s); sq = waveSum(sq);
    int wid = threadIdx.x>>6, lane = threadIdx.x&63;
    if (lane == 0) { red[wid][0] = s; red[wid][1] = sq; }
    __syncthreads();
    if (threadIdx.x < 2)
        p2[blk*2+threadIdx.x] = red[0][threadIdx.x]+red[1][threadIdx.x]+red[2][threadIdx.x]+red[3][threadIdx.x];
}

// -------- stage 2: self-prep BN2 from p2/pm; block-per-cell LDS staging --------
// grid: 2048 blocks (b*512 + r), 256 threads
__global__ __launch_bounds__(256) void k_stage2(const float* __restrict__ x1,
                         const unsigned char* __restrict__ mask32,
                         const float* __restrict__ wc2, const float* __restrict__ p2,
                         const float* __restrict__ pm, const float* __restrict__ g2,
                         const float* __restrict__ b2, float* __restrict__ x2) {
    __shared__ float wsh[1024];
    __shared__ float xin[8][64];
    __shared__ float mLDS[64];
    __shared__ float sm[16];
    __shared__ float scs[8], shs[8];
    int tid = threadIdx.x;
    int br = blockIdx.x;            // b*512 + r
    int b = br >> 9, r = br & 511;
    int d8 = r >> 6, h8 = (r >> 3) & 7, w8 = r & 7;
    for (int i = tid; i < 1024; i += 256) wsh[i] = wc2[i];
    if (tid < 16) sm[tid] = 0.f;
    const unsigned char* mb = mask32 + b*32768;
    if (tid < 64) {
        int dd = tid >> 4, hh = (tid >> 2) & 3, ww = tid & 3;
        mLDS[tid] = mb[(d8*4+dd)*1024 + (h8*4+hh)*32 + (w8*4+ww)] ? 1.f : 0.f;
    }
    __syncthreads();
    {   // p2 reduce: 512 entries, 2 per thread; sm[c*2+q]
        float v0 = p2[tid];
        atomicAdd(&sm[((tid>>4)&7)*2 + (tid&1)], v0);
        int e = tid + 256;
        float v1 = p2[e];
        atomicAdd(&sm[((e>>4)&7)*2 + (e&1)], v1);
    }
    __syncthreads();
    if (tid < 8) {
        float cnt = pm[8]+pm[9]+pm[10]+pm[11]+pm[12]+pm[13]+pm[14]+pm[15];
        cnt = fmaxf(cnt, 1.f);
        float mean = sm[tid*2] / cnt;
        float var  = sm[tid*2+1] / cnt - mean*mean;
        float s = g2[tid] * rsqrtf(var + BNEPS);
        scs[tid] = s; shs[tid] = b2[tid] - mean*s;
    }
    __syncthreads();
    if (tid < 128) {
        int c = tid >> 4, f = tid & 15;
        int dd = f >> 2, hh = f & 3;
        const float* src = x1 + (size_t)b*8*32768 + c*32768
                         + (d8*4+dd)*1024 + (h8*4+hh)*32 + w8*4;
        float4 v = *(const float4*)src;
        float sc = scs[c], sh = shs[c];
        int cbase = dd*16 + hh*4;
        float t0 = v.x*sc+sh; t0 = (t0>=0.f)?t0:LEAK*t0; xin[c][cbase+0] = t0 * mLDS[cbase+0];
        float t1 = v.y*sc+sh; t1 = (t1>=0.f)?t1:LEAK*t1; xin[c][cbase+1] = t1 * mLDS[cbase+1];
        float t2 = v.z*sc+sh; t2 = (t2>=0.f)?t2:LEAK*t2; xin[c][cbase+2] = t2 * mLDS[cbase+2];
        float t3 = v.w*sc+sh; t3 = (t3>=0.f)?t3:LEAK*t3; xin[c][cbase+3] = t3 * mLDS[cbase+3];
    }
    __syncthreads();
    int o = tid >> 4, g = tid & 15;
    float acc = 0.f;
#pragma unroll
    for (int j=0;j<4;++j) {
        int cell = g*4 + j;
        int dd = cell >> 4, hh = (cell >> 2) & 3, ww = cell & 3;
        int widx = (dd&1)*4 + (hh&1)*2 + (ww&1);
        const float* wp = wsh + o*64 + widx;
#pragma unroll
        for (int c=0;c<8;++c)
            acc += xin[c][cell] * wp[c*8];
    }
    acc += __shfl_xor(acc, 1, 64);
    acc += __shfl_xor(acc, 2, 64);
    acc += __shfl_xor(acc, 4, 64);
    acc += __shfl_xor(acc, 8, 64);
    if (g == 0) x2[((size_t)b*16 + o)*512 + r] = acc * 0.125f;
}

// -------- stage-3 stats partials --------
__global__ void k_s3stats(const float* __restrict__ x2, float* __restrict__ p3) {
    __shared__ float red[4][2];
    const float* p = x2 + (size_t)blockIdx.x * 512;   // 64 planes
    float s=0.f, sq=0.f;
    for (int i = threadIdx.x; i < 512; i += 256) { float v = p[i]; s += v; sq += v*v; }
    s = waveSum(s); sq = waveSum(sq);
    int wid = threadIdx.x>>6, lane = threadIdx.x&63;
    if (lane == 0) { red[wid][0] = s; red[wid][1] = sq; }
    __syncthreads();
    if (threadIdx.x < 2)
        p3[blockIdx.x*2+threadIdx.x] = red[0][threadIdx.x]+red[1][threadIdx.x]+red[2][threadIdx.x]+red[3][threadIdx.x];
}

// -------- stage 3: self-prep BN3 from p3/pm; wave-per-output --------
__global__ void k_stage3(const float* __restrict__ x2, const unsigned char* __restrict__ mask8,
                         const float* __restrict__ wc3, const float* __restrict__ p3,
                         const float* __restrict__ pm, const float* __restrict__ g3,
                         const float* __restrict__ b3, float* __restrict__ x3) {
    __shared__ float sm[32];
    __shared__ float scs[16], shs[16];
    int tid = threadIdx.x;
    if (tid < 32) sm[tid] = 0.f;
    __syncthreads();
    if (tid < 128) atomicAdd(&sm[((tid>>1)&15)*2 + (tid&1)], p3[tid]);
    __syncthreads();
    if (tid < 16) {
        float cnt = pm[0]+pm[1]+pm[2]+pm[3]+pm[4]+pm[5]+pm[6]+pm[7];
        cnt = fmaxf(cnt, 1.f);
        float mean = sm[tid*2] / cnt;
        float var  = sm[tid*2+1] / cnt - mean*mean;
        float s = g3[tid] * rsqrtf(var + BNEPS);
        scs[tid] = s; shs[tid] = b3[tid] - mean*s;
    }
    __syncthreads();
    int t = blockIdx.x * 4 + (tid >> 6);   // output id [0, 1024)
    int lane = tid & 63;
    int r = t & 7, bo = t >> 3;
    int o = bo & 31, b = bo >> 5;
    int d2 = (r >> 2) & 1, h2 = (r >> 1) & 1, w2 = r & 1;
    int dd = lane >> 4, hh = (lane >> 2) & 3, ww = lane & 3;
    int s8 = (d2*4+dd)*64 + (h2*4+hh)*8 + (w2*4+ww);
    const float* xb = x2 + (size_t)b*16*512;
    float w0r = wc3[o*128 + lane];
    float w1r = wc3[o*128 + 64 + lane];
    float m = mask8[b*512 + s8] ? 1.f : 0.f;
    int widx = (dd&1)*4 + (hh&1)*2 + (ww&1);
    float acc = 0.f;
#pragma unroll
    for (int c=0;c<8;++c) {
        float v = xb[c*512 + s8];
        float tt = v*scs[c] + shs[c];
        tt = (tt >= 0.f) ? tt : LEAK*tt;
        acc += tt * __shfl(w0r, c*8 + widx, 64);
    }
#pragma unroll
    for (int c=8;c<16;++c) {
        float v = xb[c*512 + s8];
        float tt = v*scs[c] + shs[c];
        tt = (tt >= 0.f) ? tt : LEAK*tt;
        acc += tt * __shfl(w1r, (c-8)*8 + widx, 64);
    }
    acc = waveSum(acc * m);
    if (lane == 0) x3[t] = acc * 0.125f;
}

// -------- final linear: wave-per-output (4,256)@(256,64)^T + blin --------
__global__ void k_linear(const float* __restrict__ x3, const float* __restrict__ wlin,
                         const float* __restrict__ blin, float* __restrict__ out) {
    int t = blockIdx.x * 4 + (threadIdx.x >> 6);   // [0,256) = b*64+j
    int lane = threadIdx.x & 63;
    int b = t >> 6, j = t & 63;
    const float* xb = x3 + b*256;
    const float* wj = wlin + j*256;
    float acc = 0.f;
#pragma unroll
    for (int k=0;k<4;++k) acc += xb[k*64+lane] * wj[k*64+lane];
    acc = waveSum(acc);
    if (lane == 0) out[t] = acc + blin[j];
}

extern "C" void kernel_launch(void* const* d_in, const int* in_sizes, int n_in,
                              void* d_out, int out_size, void* d_ws, size_t ws_size,
                              hipStream_t stream) {
    const float* pc   = (const float*)d_in[0];
    const float* w0   = (const float*)d_in[1];
    const float* g1   = (const float*)d_in[2];
    const float* b1   = (const float*)d_in[3];
    const float* wc1  = (const float*)d_in[4];
    const float* g2   = (const float*)d_in[5];
    const float* b2   = (const float*)d_in[6];
    const float* wc2  = (const float*)d_in[7];
    const float* g3   = (const float*)d_in[8];
    const float* b3   = (const float*)d_in[9];
    const float* wc3  = (const float*)d_in[10];
    const float* wlin = (const float*)d_in[11];
    const float* blin = (const float*)d_in[12];
    float* out = (float*)d_out;

    char* ws = (char*)d_ws;
    float*         dense    = (float*)(ws + OFF_DENSE);
    unsigned*      maskbits = (unsigned*)(ws + OFF_MASKBITS);
    float*         x1       = (float*)(ws + OFF_X1);
    unsigned char* mask32   = (unsigned char*)(ws + OFF_MASK32);
    unsigned char* mask8    = (unsigned char*)(ws + OFF_MASK8);
    float*         p1       = (float*)(ws + OFF_P1);
    float*         p2       = (float*)(ws + OFF_P2);
    float*         p3       = (float*)(ws + OFF_P3);
    float*         pm       = (float*)(ws + OFF_PM);
    unsigned*      nblk     = (unsigned*)(ws + OFF_NBLK);
    unsigned*      list     = (unsigned*)(ws + OFF_LIST);
    float4*        x0l      = (float4*)(ws + OFF_X0L);
    float*         x2       = (float*)(ws + OFF_X2);
    float*         x3       = (float*)(ws + OFF_X3);

    int n = in_sizes[0] / 5;
    int nb = (n + 255) / 256;

    k_init<<<256 + nb, 256, 0, stream>>>(pc, dense, (uint4*)maskbits, n);
    k_scatter<<<nb, 256, 0, stream>>>(pc, dense, maskbits, n);
    k_conv0<<<dim3(16,16,8), 512, 0, stream>>>(dense, maskbits, w0, nblk, list, x0l, mask32);
    k_stats1m<<<272, 256, 0, stream>>>(x0l, nblk, mask32, mask8, p1, pm);
    k_stage1<<<NTILE/4, 256, 0, stream>>>(x0l, list, nblk, wc1, p1, g1, b1, x1);
    k_s2stats<<<256, 256, 0, stream>>>((const float4*)x1, p2);
    k_stage2<<<2048, 256, 0, stream>>>(x1, mask32, wc2, p2, pm, g2, b2, x2);
    k_s3stats<<<64, 256, 0, stream>>>(x2, p3);
    k_stage3<<<256, 256, 0, stream>>>(x2, mask8, wc3, p3, pm, g3, b3, x3);
    k_linear<<<64, 256, 0, stream>>>(x3, wlin, blin, out);
}

// Round 21
// 100.246 us; speedup vs baseline: 1.0651x; 1.0651x over previous
//
#include <hip/hip_runtime.h>

#define SS 128
#define S3 (SS*SS*SS)
#define NBATCH 4
#define LEAK 0.01f
#define BNEPS 1e-4f
#define NTILE 16384          // 4 batches * 16^3 tiles of 8^3
#define MAXSLOT 64

// ---------------- workspace layout (bytes) ----------------
constexpr size_t OFF_DENSE    = 0;                                   // f32 [4][128^3] (NOT zeroed; masked on read)
constexpr size_t OFF_MASKBITS = OFF_DENSE + (size_t)NBATCH*S3*4;     // u32 bitgrid 1MB (zeroed by k_init)
constexpr size_t OFF_X1       = OFF_MASKBITS + (size_t)NBATCH*S3/8;  // f32 [4][8][32^3] (written by stage1)
constexpr size_t OFF_MASK32   = OFF_X1 + (size_t)NBATCH*8*32768*4;   // u8 [4][32^3] (written by conv0)
constexpr size_t OFF_MASK8    = OFF_MASK32 + (size_t)NBATCH*32768;   // u8 [4][8^3]  (written by k_stats1m)
constexpr size_t OFF_STATS    = OFF_MASK8 + (size_t)NBATCH*512;      // f32 [64] coefs
constexpr size_t OFF_P1       = OFF_STATS + 256;                     // f32 [256][9]
constexpr size_t OFF_P2       = OFF_P1 + 256*9*4;                    // f32 [256][2]
constexpr size_t OFF_P3       = OFF_P2 + 256*2*4;                    // f32 [64][2]
constexpr size_t OFF_PM       = OFF_P3 + 64*2*4;                     // f32 [16] mask-count partials
constexpr size_t OFF_NBLK     = OFF_PM + 16*4;                       // u32 [16384]
constexpr size_t OFF_LIST     = OFF_NBLK + NTILE*4;                  // u32 [16384][64]
constexpr size_t OFF_X0L      = OFF_LIST + (size_t)NTILE*MAXSLOT*4;  // f32x4 [16384][64]
constexpr size_t OFF_X2       = OFF_X0L + (size_t)NTILE*MAXSLOT*16;  // f32 [4][16][8^3]
constexpr size_t OFF_X3       = OFF_X2 + (size_t)NBATCH*16*512*4;    // f32 [4][32][2^3]

// stats float slots: [0]=cnt2 [1]=cnt8 [2..5]=sc1 [6..9]=sh1 [10..17]=sc2 [18..25]=sh2
//                    [26..41]=sc3 [42..57]=sh3

__device__ inline float waveSum(float v) {
#pragma unroll
    for (int off = 32; off; off >>= 1) v += __shfl_xor(v, off, 64);
    return v;
}

// -------- init: zero maskbits (blocks 0..255) + zero occupied dense voxels (rest) --------
__global__ void k_init(const float* __restrict__ pc, float* __restrict__ dense,
                       uint4* __restrict__ maskbits4, int n) {
    int blk = blockIdx.x;
    if (blk < 256) {
        maskbits4[blk * 256 + threadIdx.x] = make_uint4(0u, 0u, 0u, 0u);
        return;
    }
    int i = (blk - 256) * 256 + threadIdx.x;
    if (i >= n) return;
    int d = (int)pc[i*5+0], h = (int)pc[i*5+1], w = (int)pc[i*5+2], b = (int)pc[i*5+3];
    dense[(((size_t)b*SS + d)*SS + h)*SS + w] = 0.f;
}

// -------- accumulate features; dedup via bit grid --------
__global__ void k_scatter(const float* __restrict__ pc, float* __restrict__ dense,
                          unsigned* __restrict__ maskbits, int n) {
    int i = blockIdx.x * blockDim.x + threadIdx.x;
    if (i >= n) return;
    float c0 = pc[i*5+0], c1 = pc[i*5+1], c2 = pc[i*5+2], cb = pc[i*5+3], f = pc[i*5+4];
    int d = (int)c0, h = (int)c1, w = (int)c2, b = (int)cb;
    unsigned vox = (((unsigned)b*SS + d)*SS + h)*SS + w;
    atomicAdd(&dense[vox], f);
    atomicOr(&maskbits[vox >> 5], 1u << (vox & 31));
}

// -------- conv0: 8x8x64(+halo) slab per block; float4 staging; sparse queue compute --------
// grid: (16 h-tiles, 16 d-tiles, 4 batches * 2 w-halves), 512 threads
__global__ __launch_bounds__(512) void k_conv0(const float* __restrict__ dense,
                                               const unsigned* __restrict__ maskbits,
                                               const float* __restrict__ w0g,
                                               unsigned* __restrict__ nblk,
                                               unsigned* __restrict__ list,
                                               float4* __restrict__ x0l,
                                               unsigned char* __restrict__ mask32) {
    __shared__ float lds[10*10*68];           // halo slab: col 0 = w0-1, 1..64 = w0.., 65 = w0+64
    __shared__ float ws[108];
    __shared__ unsigned short wtot[8][8];     // per-subtile per-wave occupied counts
    __shared__ unsigned queue[8*MAXSLOT];     // compact work items
    __shared__ unsigned char cellocc[8][8];
    int tid = threadIdx.x;
    int lane = tid & 63, wid = tid >> 6;
    int th = blockIdx.x, td = blockIdx.y;
    int zb = blockIdx.z;                      // b*2 + wh
    int b = zb >> 1, wh = zb & 1;
    int d0 = td*8, h0 = th*8, w0 = wh*64;
    if (tid < 108) ws[tid] = w0g[tid];
    if (tid < 64) cellocc[tid>>3][tid&7] = 0;
    const float* dn = dense + (size_t)b * S3;
    // stage main slab: 100 rows x 16 float4 (mask-gated); thread-linear (row,quad)
    for (int idx = tid; idx < 1600; idx += 512) {
        int r = idx >> 4, q = idx & 15;
        int dz = r / 10, dy = r - dz*10;
        int gz = d0 - 1 + dz, gy = h0 - 1 + dy;
        float4 v = make_float4(0.f, 0.f, 0.f, 0.f);
        if ((unsigned)gz < SS && (unsigned)gy < SS) {
            unsigned row = ((unsigned)b*SS + gz)*SS + gy;
            int gx = w0 + q*4;
            v = *(const float4*)(dn + ((size_t)gz*SS + gy)*SS + gx);
            unsigned mword = maskbits[row*4 + (gx >> 5)];
            int sh = gx & 31;
            if (!((mword >> (sh+0)) & 1u)) v.x = 0.f;
            if (!((mword >> (sh+1)) & 1u)) v.y = 0.f;
            if (!((mword >> (sh+2)) & 1u)) v.z = 0.f;
            if (!((mword >> (sh+3)) & 1u)) v.w = 0.f;
        }
        float* lrow = lds + r*68 + 1 + q*4;
        lrow[0]=v.x; lrow[1]=v.y; lrow[2]=v.z; lrow[3]=v.w;
    }
    // halo columns: 100 rows x 2 sides
    for (int idx = tid; idx < 200; idx += 512) {
        int r = idx >> 1, side = idx & 1;
        int dz = r / 10, dy = r - dz*10;
        int gz = d0 - 1 + dz, gy = h0 - 1 + dy;
        int hgx = side ? (w0 + 64) : (w0 - 1);
        float hv = 0.f;
        if ((unsigned)gz < SS && (unsigned)gy < SS && (unsigned)hgx < SS) {
            unsigned row = ((unsigned)b*SS + gz)*SS + gy;
            float v = dn[((size_t)gz*SS + gy)*SS + hgx];
            unsigned mword = maskbits[row*4 + (hgx >> 5)];
            hv = ((mword >> (hgx & 31)) & 1u) ? v : 0.f;
        }
        lds[r*68 + (side ? 65 : 0)] = hv;
    }
    // occupancy scan: 8 subtile occ bits from this half's two mask words
    int tz = wid, ty = (tid >> 3) & 7, tx = tid & 7;
    int gz = d0 + tz, gy = h0 + ty;
    uint4 rb = ((const uint4*)maskbits)[((unsigned)b*SS + gz)*SS + gy];
    unsigned loW = wh ? rb.z : rb.x;          // words for w0..w0+31 / +32..+63
    unsigned hiW = wh ? rb.w : rb.y;
    unsigned occ8 = 0;
#pragma unroll
    for (int s=0;s<8;++s) {
        unsigned word = (s < 4) ? loW : hiW;
        occ8 |= (((word >> (((s&3)<<3) + tx)) & 1u) << s);
    }
    unsigned long long ballArr[8];
#pragma unroll
    for (int s=0;s<8;++s) {
        ballArr[s] = __ballot((occ8 >> s) & 1u);
        if (lane == 0) wtot[s][wid] = (unsigned short)__popcll(ballArr[s]);
    }
    __syncthreads();   // slab staged; wtot, cellocc-zero visible
    unsigned long long lmask = (1ull << lane) - 1ull;
    int blkbase = ((b*16 + td)*16 + th)*16 + wh*8;
    unsigned qb = 0;   // running queue offset (uniform across block)
#pragma unroll
    for (int s=0;s<8;++s) {
        unsigned base = 0, total = 0;
#pragma unroll
        for (int j=0;j<8;++j) { unsigned t = wtot[s][j]; if (j < wid) base += t; total += t; }
        unsigned tc = total < MAXSLOT ? total : MAXSLOT;
        if ((occ8 >> s) & 1u) {
            unsigned slot = base + (unsigned)__popcll(ballArr[s] & lmask);
            if (slot < MAXSLOT) queue[qb + slot] = (unsigned)tid | (s<<9) | (slot<<13);
            cellocc[s][((tz>>2)<<2) | ((ty>>2)<<1) | (tx>>2)] = 1;
        }
        qb += tc;
    }
    if (tid < 8) {
        unsigned total = 0;
#pragma unroll
        for (int j=0;j<8;++j) total += wtot[tid][j];
        nblk[blkbase + tid] = total < MAXSLOT ? total : MAXSLOT;
    }
    __syncthreads();   // queue + cellocc complete
    if (tid < 64) {
        int s = tid >> 3, c = tid & 7;
        int cz = (c>>2)&1, cy = (c>>1)&1, cx = c&1;
        mask32[b*32768 + ((d0>>2)+cz)*1024 + ((h0>>2)+cy)*32 + wh*16 + s*2+cx] = cellocc[s][c];
    }
    // drain queue: one conv per occupied voxel
    for (unsigned i = tid; i < qb; i += 512) {
        unsigned e = queue[i];
        int et = e & 511, es = (e>>9) & 15, eslot = e >> 13;
        int ez = et >> 6, ey = (et>>3) & 7, ex = et & 7;
        int egx = es*8 + ex;                 // local col within half [0,63]
        float a0=0.f, a1=0.f, a2=0.f, a3=0.f;
#pragma unroll
        for (int kd=0; kd<3; ++kd)
#pragma unroll
            for (int kh=0; kh<3; ++kh)
#pragma unroll
                for (int kw=0; kw<3; ++kw) {
                    float v = lds[((ez+kd)*10 + ey+kh)*68 + egx + kw];
                    int kk = kd*9 + kh*3 + kw;
                    a0 += v*ws[kk]; a1 += v*ws[27+kk]; a2 += v*ws[54+kk]; a3 += v*ws[81+kk];
                }
        int blk = blkbase + es;
        unsigned vox = (((unsigned)b*SS + d0+ez)*SS + h0+ey)*SS + (w0 + egx);
        list[(size_t)blk*MAXSLOT + eslot] = vox;
        x0l[(size_t)blk*MAXSLOT + eslot] = make_float4(a0, a1, a2, a3);
    }
}

// -------- fused: BN1 stats partials (blocks 0..255) + mask8/cnt partials (256..271) --------
__global__ void k_stats1m(const float4* __restrict__ x0l, const unsigned* __restrict__ nblk,
                          const unsigned char* __restrict__ mask32, unsigned char* __restrict__ mask8,
                          float* __restrict__ p1, float* __restrict__ pm) {
    int tid = threadIdx.x;
    int bid = blockIdx.x;
    if (bid < 256) {
        __shared__ float red[4][9];
        int tid0 = bid * 256 + tid;
        float a[9] = {0,0,0,0,0,0,0,0,0};
        for (int s = tid0; s < NTILE*MAXSLOT; s += 65536) {
            int blk = s >> 6, sl = s & 63;
            if (sl < (int)nblk[blk]) {
                float4 v = x0l[s];
                a[0]+=v.x; a[1]+=v.y; a[2]+=v.z; a[3]+=v.w;
                a[4]+=v.x*v.x; a[5]+=v.y*v.y; a[6]+=v.z*v.z; a[7]+=v.w*v.w;
                a[8]+=1.f;
            }
        }
#pragma unroll
        for (int k=0;k<9;++k) a[k] = waveSum(a[k]);
        int wid = tid>>6, lane = tid&63;
        if (lane < 9) red[wid][lane] = a[lane];
        __syncthreads();
        if (tid < 9) p1[bid*9+tid] = red[0][tid]+red[1][tid]+red[2][tid]+red[3][tid];
        return;
    }
    // mask path
    __shared__ float redm[4];
    int blk = bid - 256;
    float c = 0.f;
    if (blk < 8) {          // mask8: 8 blocks x 256 entries; partial -> cnt8
        int i = blk*256 + tid;
        int b = i>>9, r = i&511;
        int d8 = r>>6, h8 = (r>>3)&7, w8 = r&7;
        const unsigned char* m = mask32 + b*32768;
        unsigned v = 0;
#pragma unroll
        for (int dz=0;dz<2;++dz)
#pragma unroll
            for (int dy=0;dy<2;++dy)
#pragma unroll
                for (int dx=0;dx<2;++dx)
                    v |= m[(2*d8+dz)*1024 + (2*h8+dy)*32 + (2*w8+dx)];
        mask8[i] = (unsigned char)v;
        c = (float)v;
    } else {                // cnt2: 2048 threads x 4 uint4 = full 128KB of mask32
        const uint4* m4 = (const uint4*)mask32;
        int base = ((blk-8)*256 + tid)*4;
#pragma unroll
        for (int j=0;j<4;++j) {
            uint4 x = m4[base+j];
            c += (float)(__popc(x.x) + __popc(x.y) + __popc(x.z) + __popc(x.w));
        }
    }
    c = waveSum(c);
    if ((tid & 63) == 0) redm[tid>>6] = c;
    __syncthreads();
    if (tid == 0) pm[blk] = redm[0]+redm[1]+redm[2]+redm[3];
}

// -------- final reduce for BN1 + count totals --------
__global__ __launch_bounds__(256) void k_prep1(const float* __restrict__ p1,
        const float* __restrict__ pm, const float* __restrict__ g1,
        const float* __restrict__ b1, float* __restrict__ stats) {
    __shared__ float red[4][9];
    __shared__ float tot[9];
    int tid = threadIdx.x;
    int wid = tid>>6, lane = tid&63;
    float a[9];
#pragma unroll
    for (int k=0;k<9;++k) a[k] = p1[tid*9+k];
#pragma unroll
    for (int k=0;k<9;++k) a[k] = waveSum(a[k]);
    if (lane < 9) red[wid][lane] = a[lane];
    __syncthreads();
    if (tid < 9) tot[tid] = red[0][tid]+red[1][tid]+red[2][tid]+red[3][tid];
    __syncthreads();
    if (tid < 4) {
        float cnt = fmaxf(tot[8], 1.f);
        float mean = tot[tid] / cnt;
        float var  = tot[4+tid] / cnt - mean*mean;
        float s = g1[tid] * rsqrtf(var + BNEPS);
        stats[2+tid] = s; stats[6+tid] = b1[tid] - mean*s;
    }
    if (tid == 4) { float s=0.f; for (int j=8;j<16;++j) s += pm[j]; stats[0] = s; }   // cnt2
    if (tid == 5) { float s=0.f; for (int j=0;j<8;++j)  s += pm[j]; stats[1] = s; }   // cnt8
}

// -------- stage 1: LDS-accumulated gather; BN1+LReLU+conv+pool/8 -> x1 (no global atomics) --------
__global__ void k_stage1(const float4* __restrict__ x0l, const unsigned* __restrict__ list,
                         const unsigned* __restrict__ nblk, const float* __restrict__ wc1,
                         const float* __restrict__ stats, float* __restrict__ x1) {
    __shared__ float acc[256];     // [tile4][o8][cell8]
    __shared__ float wsh[256];
    __shared__ float sc[4], sh[4];
    int tid = threadIdx.x;
    wsh[tid] = wc1[tid];
    acc[tid] = 0.f;
    if (tid < 4) { sc[tid] = stats[2+tid]; sh[tid] = stats[6+tid]; }
    __syncthreads();
    int s = blockIdx.x * 256 + tid;
    int blk = s >> 6, sl = s & 63;
    int lt = tid >> 6;                 // local tile 0..3
    if (sl < (int)nblk[blk]) {
        unsigned vox = list[s];
        float4 v = x0l[s];
        int w = vox & 127, h = (vox>>7)&127, d = (vox>>14)&127;
        float y[4];
        float t0 = v.x*sc[0]+sh[0]; y[0] = t0 >= 0.f ? t0 : LEAK*t0;
        float t1 = v.y*sc[1]+sh[1]; y[1] = t1 >= 0.f ? t1 : LEAK*t1;
        float t2 = v.z*sc[2]+sh[2]; y[2] = t2 >= 0.f ? t2 : LEAK*t2;
        float t3 = v.w*sc[3]+sh[3]; y[3] = t3 >= 0.f ? t3 : LEAK*t3;
        int widx = (d&1)*4 + (h&1)*2 + (w&1);
        int cell = ((d>>2)&1)*4 + ((h>>2)&1)*2 + ((w>>2)&1);
        float* ap = acc + lt*64 + cell;
#pragma unroll
        for (int o=0;o<8;++o) {
            const float* wp = wsh + o*32 + widx;
            float contrib = y[0]*wp[0] + y[1]*wp[8] + y[2]*wp[16] + y[3]*wp[24];
            atomicAdd(ap + o*8, contrib * 0.125f);
        }
    }
    __syncthreads();
    // write out: tid -> (lt, o, cell); every x1 location covered exactly once
    int rem = tid & 63, o = rem >> 3, cell = rem & 7;
    int blk2 = blockIdx.x*4 + (tid >> 6);
    int ss = blk2 & 15, th = (blk2>>4)&15, td = (blk2>>8)&15, b = blk2>>12;
    int cz = (cell>>2)&1, cy = (cell>>1)&1, cx = cell&1;
    x1[(size_t)b*8*32768 + o*32768 + (td*2+cz)*1024 + (th*2+cy)*32 + ss*2+cx] = acc[tid];
}

// -------- stage-2 stats partials --------
__global__ void k_s2stats(const float4* __restrict__ x1v, float* __restrict__ p2) {
    __shared__ float red[4][2];
    int blk = blockIdx.x;              // 256 = plane(32) x chunk(8)
    int plane = blk >> 3, chunk = blk & 7;
    const float4* p = x1v + (size_t)plane*8192 + chunk*1024;
    float s=0.f, sq=0.f;
    for (int i = threadIdx.x; i < 1024; i += 256) {
        float4 v = p[i];
        s  += v.x+v.y+v.z+v.w;
        sq += v.x*v.x+v.y*v.y+v.z*v.z+v.w*v.w;
    }
    s = waveSum(s); sq = waveSum(sq);
    int wid = threadIdx.x>>6, lane = threadIdx.x&63;
    if (lane == 0) { red[wid][0] = s; red[wid][1] = sq; }
    __syncthreads();
    if (threadIdx.x < 2)
        p2[blk*2+threadIdx.x] = red[0][threadIdx.x]+red[1][threadIdx.x]+red[2][threadIdx.x]+red[3][threadIdx.x];
}

__global__ void k_prep2(const float* __restrict__ p2, const float* __restrict__ g2,
                        const float* __restrict__ b2, float* __restrict__ stats) {
    __shared__ float sm[16];
    int tid = threadIdx.x;
    if (tid < 16) {
        int c = tid & 7, q = tid >> 3;
        float s = 0.f;
        for (int b=0;b<4;++b)
            for (int ch=0;ch<8;++ch)
                s += p2[((b*8+c)*8+ch)*2 + q];
        sm[tid] = s;
    }
    __syncthreads();
    if (tid < 8) {
        float cnt = fmaxf(stats[0], 1.f);
        float mean = sm[tid] / cnt;
        float var  = sm[8+tid] / cnt - mean*mean;
        float s = g2[tid] * rsqrtf(var + BNEPS);
        stats[10+tid] = s; stats[18+tid] = b2[tid] - mean*s;
    }
}

// -------- stage 2: block-per-cell LDS staging; BN2+LReLU+mask once, 16 o from LDS --------
// grid: 2048 blocks (b*512 + r), 256 threads
__global__ __launch_bounds__(256) void k_stage2(const float* __restrict__ x1,
                         const unsigned char* __restrict__ mask32,
                         const float* __restrict__ wc2, const float* __restrict__ stats,
                         float* __restrict__ x2) {
    __shared__ float wsh[1024];
    __shared__ float xin[8][64];
    __shared__ float mLDS[64];
    __shared__ float scs[8], shs[8];
    int tid = threadIdx.x;
    int br = blockIdx.x;            // b*512 + r
    int b = br >> 9, r = br & 511;
    int d8 = r >> 6, h8 = (r >> 3) & 7, w8 = r & 7;
    for (int i = tid; i < 1024; i += 256) wsh[i] = wc2[i];
    if (tid < 8) { scs[tid] = stats[10+tid]; shs[tid] = stats[18+tid]; }
    const unsigned char* mb = mask32 + b*32768;
    if (tid < 64) {
        int dd = tid >> 4, hh = (tid >> 2) & 3, ww = tid & 3;
        mLDS[tid] = mb[(d8*4+dd)*1024 + (h8*4+hh)*32 + (w8*4+ww)] ? 1.f : 0.f;
    }
    __syncthreads();
    // stage 8ch x 64 cells with BN+LReLU+mask applied once
    if (tid < 128) {
        int c = tid >> 4, f = tid & 15;
        int dd = f >> 2, hh = f & 3;
        const float* src = x1 + (size_t)b*8*32768 + c*32768
                         + (d8*4+dd)*1024 + (h8*4+hh)*32 + w8*4;
        float4 v = *(const float4*)src;
        float sc = scs[c], sh = shs[c];
        int cbase = dd*16 + hh*4;
        float t0 = v.x*sc+sh; t0 = (t0>=0.f)?t0:LEAK*t0; xin[c][cbase+0] = t0 * mLDS[cbase+0];
        float t1 = v.y*sc+sh; t1 = (t1>=0.f)?t1:LEAK*t1; xin[c][cbase+1] = t1 * mLDS[cbase+1];
        float t2 = v.z*sc+sh; t2 = (t2>=0.f)?t2:LEAK*t2; xin[c][cbase+2] = t2 * mLDS[cbase+2];
        float t3 = v.w*sc+sh; t3 = (t3>=0.f)?t3:LEAK*t3; xin[c][cbase+3] = t3 * mLDS[cbase+3];
    }
    __syncthreads();
    // compute: thread = (o, g); 16 threads per o, 4 cells each
    int o = tid >> 4, g = tid & 15;
    float acc = 0.f;
#pragma unroll
    for (int j=0;j<4;++j) {
        int cell = g*4 + j;
        int dd = cell >> 4, hh = (cell >> 2) & 3, ww = cell & 3;
        int widx = (dd&1)*4 + (hh&1)*2 + (ww&1);
        const float* wp = wsh + o*64 + widx;
#pragma unroll
        for (int c=0;c<8;++c)
            acc += xin[c][cell] * wp[c*8];
    }
    acc += __shfl_xor(acc, 1, 64);
    acc += __shfl_xor(acc, 2, 64);
    acc += __shfl_xor(acc, 4, 64);
    acc += __shfl_xor(acc, 8, 64);
    if (g == 0) x2[((size_t)b*16 + o)*512 + r] = acc * 0.125f;
}

// -------- stage-3 stats partials --------
__global__ void k_s3stats(const float* __restrict__ x2, float* __restrict__ p3) {
    __shared__ float red[4][2];
    const float* p = x2 + (size_t)blockIdx.x * 512;   // 64 planes
    float s=0.f, sq=0.f;
    for (int i = threadIdx.x; i < 512; i += 256) { float v = p[i]; s += v; sq += v*v; }
    s = waveSum(s); sq = waveSum(sq);
    int wid = threadIdx.x>>6, lane = threadIdx.x&63;
    if (lane == 0) { red[wid][0] = s; red[wid][1] = sq; }
    __syncthreads();
    if (threadIdx.x < 2)
        p3[blockIdx.x*2+threadIdx.x] = red[0][threadIdx.x]+red[1][threadIdx.x]+red[2][threadIdx.x]+red[3][threadIdx.x];
}

__global__ void k_prep3(const float* __restrict__ p3, const float* __restrict__ g3,
                        const float* __restrict__ b3, float* __restrict__ stats) {
    __shared__ float sm[32];
    int tid = threadIdx.x;
    if (tid < 32) {
        int c = tid & 15, q = tid >> 4;
        float s = 0.f;
        for (int b=0;b<4;++b) s += p3[(b*16+c)*2 + q];
        sm[tid] = s;
    }
    __syncthreads();
    if (tid < 16) {
        float cnt = fmaxf(stats[1], 1.f);
        float mean = sm[tid] / cnt;
        float var  = sm[16+tid] / cnt - mean*mean;
        float s = g3[tid] * rsqrtf(var + BNEPS);
        stats[26+tid] = s; stats[42+tid] = b3[tid] - mean*s;
    }
}

// -------- stage 3: wave-per-output; BN3+LReLU+mask, conv (16->32), pool/8 -> x3 --------
__global__ void k_stage3(const float* __restrict__ x2, const unsigned char* __restrict__ mask8,
                         const float* __restrict__ wc3, const float* __restrict__ stats,
                         float* __restrict__ x3) {
    int t = blockIdx.x * 4 + (threadIdx.x >> 6);   // output id [0, 1024)
    int lane = threadIdx.x & 63;
    int r = t & 7, bo = t >> 3;
    int o = bo & 31, b = bo >> 5;
    int d2 = (r >> 2) & 1, h2 = (r >> 1) & 1, w2 = r & 1;
    int dd = lane >> 4, hh = (lane >> 2) & 3, ww = lane & 3;
    int s8 = (d2*4+dd)*64 + (h2*4+hh)*8 + (w2*4+ww);
    const float* xb = x2 + (size_t)b*16*512;
    float w0r = wc3[o*128 + lane];                 // weights [c<8][widx]
    float w1r = wc3[o*128 + 64 + lane];            // weights [c>=8][widx]
    float m = mask8[b*512 + s8] ? 1.f : 0.f;
    int widx = (dd&1)*4 + (hh&1)*2 + (ww&1);
    float acc = 0.f;
#pragma unroll
    for (int c=0;c<8;++c) {
        float v = xb[c*512 + s8];
        float tt = v*stats[26+c] + stats[42+c];
        tt = (tt >= 0.f) ? tt : LEAK*tt;
        acc += tt * __shfl(w0r, c*8 + widx, 64);
    }
#pragma unroll
    for (int c=8;c<16;++c) {
        float v = xb[c*512 + s8];
        float tt = v*stats[26+c] + stats[42+c];
        tt = (tt >= 0.f) ? tt : LEAK*tt;
        acc += tt * __shfl(w1r, (c-8)*8 + widx, 64);
    }
    acc = waveSum(acc * m);
    if (lane == 0) x3[t] = acc * 0.125f;
}

// -------- final linear: wave-per-output (4,256)@(256,64)^T + blin --------
__global__ void k_linear(const float* __restrict__ x3, const float* __restrict__ wlin,
                         const float* __restrict__ blin, float* __restrict__ out) {
    int t = blockIdx.x * 4 + (threadIdx.x >> 6);   // [0,256) = b*64+j
    int lane = threadIdx.x & 63;
    int b = t >> 6, j = t & 63;
    const float* xb = x3 + b*256;
    const float* wj = wlin + j*256;
    float acc = 0.f;
#pragma unroll
    for (int k=0;k<4;++k) acc += xb[k*64+lane] * wj[k*64+lane];
    acc = waveSum(acc);
    if (lane == 0) out[t] = acc + blin[j];
}

extern "C" void kernel_launch(void* const* d_in, const int* in_sizes, int n_in,
                              void* d_out, int out_size, void* d_ws, size_t ws_size,
                              hipStream_t stream) {
    const float* pc   = (const float*)d_in[0];
    const float* w0   = (const float*)d_in[1];
    const float* g1   = (const float*)d_in[2];
    const float* b1   = (const float*)d_in[3];
    const float* wc1  = (const float*)d_in[4];
    const float* g2   = (const float*)d_in[5];
    const float* b2   = (const float*)d_in[6];
    const float* wc2  = (const float*)d_in[7];
    const float* g3   = (const float*)d_in[8];
    const float* b3   = (const float*)d_in[9];
    const float* wc3  = (const float*)d_in[10];
    const float* wlin = (const float*)d_in[11];
    const float* blin = (const float*)d_in[12];
    float* out = (float*)d_out;

    char* ws = (char*)d_ws;
    float*         dense    = (float*)(ws + OFF_DENSE);
    unsigned*      maskbits = (unsigned*)(ws + OFF_MASKBITS);
    float*         x1       = (float*)(ws + OFF_X1);
    unsigned char* mask32   = (unsigned char*)(ws + OFF_MASK32);
    unsigned char* mask8    = (unsigned char*)(ws + OFF_MASK8);
    float*         stats    = (float*)(ws + OFF_STATS);
    float*         p1       = (float*)(ws + OFF_P1);
    float*         p2       = (float*)(ws + OFF_P2);
    float*         p3       = (float*)(ws + OFF_P3);
    float*         pm       = (float*)(ws + OFF_PM);
    unsigned*      nblk     = (unsigned*)(ws + OFF_NBLK);
    unsigned*      list     = (unsigned*)(ws + OFF_LIST);
    float4*        x0l      = (float4*)(ws + OFF_X0L);
    float*         x2       = (float*)(ws + OFF_X2);
    float*         x3       = (float*)(ws + OFF_X3);

    int n = in_sizes[0] / 5;
    int nb = (n + 255) / 256;

    k_init<<<256 + nb, 256, 0, stream>>>(pc, dense, (uint4*)maskbits, n);
    k_scatter<<<nb, 256, 0, stream>>>(pc, dense, maskbits, n);
    k_conv0<<<dim3(16,16,8), 512, 0, stream>>>(dense, maskbits, w0, nblk, list, x0l, mask32);
    k_stats1m<<<272, 256, 0, stream>>>(x0l, nblk, mask32, mask8, p1, pm);
    k_prep1<<<1, 256, 0, stream>>>(p1, pm, g1, b1, stats);
    k_stage1<<<NTILE/4, 256, 0, stream>>>(x0l, list, nblk, wc1, stats, x1);
    k_s2stats<<<256, 256, 0, stream>>>((const float4*)x1, p2);
    k_prep2<<<1, 64, 0, stream>>>(p2, g2, b2, stats);
    k_stage2<<<2048, 256, 0, stream>>>(x1, mask32, wc2, stats, x2);
    k_s3stats<<<64, 256, 0, stream>>>(x2, p3);
    k_prep3<<<1, 64, 0, stream>>>(p3, g3, b3, stats);
    k_stage3<<<256, 256, 0, stream>>>(x2, mask8, wc3, stats, x3);
    k_linear<<<64, 256, 0, stream>>>(x3, wlin, blin, out);
}